// Round 11
// baseline (140.812 us; speedup 1.0000x reference)
//
#include <hip/hip_runtime.h>
#include <cfloat>
#include <climits>

#define B_DIM 16
#define C_DIM 64
#define N_DIM 2048
#define O_DIM 64
#define K_NN  3

typedef __attribute__((ext_vector_type(8))) short bf16x8;
typedef __attribute__((ext_vector_type(4))) float floatx4;

// async global->LDS DMA, 16B/lane: LDS dest = uniform base + lane*16
#define GLDS16(gsrc, ldst)                                        \
  __builtin_amdgcn_global_load_lds(                               \
      (const __attribute__((address_space(1))) void*)(gsrc),      \
      (__attribute__((address_space(3))) void*)(ldst), 16, 0, 0)

__device__ __forceinline__ unsigned short f32_to_bf16_rne(float f) {
  unsigned int u = __float_as_uint(f);
  return (unsigned short)((u + 0x7fffu + ((u >> 16) & 1u)) >> 16);
}
__device__ __forceinline__ float bf16_to_f32(unsigned short h) {
  return __uint_as_float(((unsigned int)h) << 16);
}

// med3 on u32 (compiler pattern-matches to v_med3_u32)
__device__ __forceinline__ unsigned med3u(unsigned a, unsigned b, unsigned c) {
  unsigned mn = min(a, b), mx = max(a, b);
  return max(mn, min(mx, c));
}

// paired (packed-key, j) branchless top-4 insert — merge phase only
__device__ __forceinline__ void ins4p(unsigned u, int jv, unsigned* k, int* j) {
  bool c3 = u < k[3], c2 = u < k[2], c1 = u < k[1], c0 = u < k[0];
  k[3] = c2 ? k[2] : (c3 ? u  : k[3]);
  j[3] = c2 ? j[2] : (c3 ? jv : j[3]);
  k[2] = c1 ? k[1] : (c2 ? u  : k[2]);
  j[2] = c1 ? j[1] : (c2 ? jv : j[2]);
  k[1] = c0 ? k[0] : (c1 ? u  : k[1]);
  j[1] = c0 ? j[0] : (c1 ? jv : j[1]);
  k[0] = c0 ? u  : k[0];
  j[0] = c0 ? jv : j[0];
}

// branchless sorted-top-3 insert on u64 keys
__device__ __forceinline__ void ins3u64(unsigned long long v,
                                        unsigned long long& k0,
                                        unsigned long long& k1,
                                        unsigned long long& k2) {
  bool c0 = v < k0, c1 = v < k1, c2 = v < k2;
  k2 = c1 ? k1 : (c2 ? v : k2);
  k1 = c0 ? k0 : (c1 ? v : k1);
  k0 = c0 ? v : k0;
}

// ---- kernel 1: x -> xT fp32 [B][N][C], bf16 hi/lo split (chunk-swizzled:
// 16B chunk q of row n stored at q^(n&7)), fp64 norms nd, fp32 norms+512.
// Blocks >= 512 do the W transpose. ----
__global__ __launch_bounds__(256) void prep_kernel(
    const float* __restrict__ x, float* __restrict__ xT,
    unsigned short* __restrict__ xTh, unsigned short* __restrict__ xTl,
    double* __restrict__ nd, float* __restrict__ nf,
    const float* __restrict__ W, float* __restrict__ Wt) {
  int bid = blockIdx.x;
  int t = threadIdx.x;
  if (bid >= 512) {                  // W transpose: 48 blocks
    int t2 = (bid - 512) * 256 + t;  // 12288 = O * C * K
    int o  = t2 / (C_DIM * K_NN);
    int ck = t2 - o * (C_DIM * K_NN);
    Wt[ck * O_DIM + o] = W[t2];
    return;
  }
  __shared__ __align__(16) float xs[C_DIM][68];
  int b  = bid >> 5;
  int n0 = (bid & 31) * 64;
  const float* xb = x + (size_t)b * C_DIM * N_DIM;
  #pragma unroll
  for (int r = 0; r < 4; ++r) {
    int idx = r * 256 + t;           // 1024 float4 tasks
    int c = idx >> 4;
    int qq = idx & 15;
    *(float4*)&xs[c][qq * 4] = *(const float4*)(xb + (size_t)c * N_DIM + n0 + qq * 4);
  }
  __syncthreads();
  int n = t >> 2, cg = t & 3;        // 64 n x 4 c-groups of 16
  float v[16];
  #pragma unroll
  for (int cc = 0; cc < 16; ++cc) v[cc] = xs[cg * 16 + cc][n];
  double ps = 0.0;
  #pragma unroll
  for (int cc = 0; cc < 16; ++cc) ps = fma((double)v[cc], (double)v[cc], ps);
  ps += __shfl_xor(ps, 1, 64);
  ps += __shfl_xor(ps, 2, 64);       // lanes t^1,t^2 share n
  size_t row = (size_t)b * N_DIM + n0 + n;
  #pragma unroll
  for (int qq = 0; qq < 4; ++qq) {
    float4 wv; wv.x = v[qq*4]; wv.y = v[qq*4+1]; wv.z = v[qq*4+2]; wv.w = v[qq*4+3];
    *(float4*)&xT[row * C_DIM + cg * 16 + qq * 4] = wv;
  }
  unsigned short hh[16], ll[16];
  #pragma unroll
  for (int cc = 0; cc < 16; ++cc) {
    hh[cc] = f32_to_bf16_rne(v[cc]);
    ll[cc] = f32_to_bf16_rne(v[cc] - bf16_to_f32(hh[cc]));
  }
  #pragma unroll
  for (int e = 0; e < 2; ++e) {
    int phys = (2 * cg + e) ^ (n & 7);
    unsigned int hp[4], lp[4];
    #pragma unroll
    for (int xk = 0; xk < 4; ++xk) {
      hp[xk] = (unsigned)hh[e*8 + 2*xk] | ((unsigned)hh[e*8 + 2*xk + 1] << 16);
      lp[xk] = (unsigned)ll[e*8 + 2*xk] | ((unsigned)ll[e*8 + 2*xk + 1] << 16);
    }
    ((uint4*)xTh)[row * 8 + phys] = *(uint4*)hp;
    ((uint4*)xTl)[row * 8 + phys] = *(uint4*)lp;
  }
  if (cg == 0) {
    nd[row] = ps;
    nf[row] = (float)ps + 512.0f;    // pre-biased: key' = fma(-2,acc,nf) > 0
  }
}

// ---- kernel 2: split-bf16 MFMA distance sweep, packed-u32 top-4,
// double-buffered global_load_lds staging ----
// r6 sync structure UNCHANGED (r7's counted-vmcnt rework regressed 2.2x).
// ROUND-11 changes, both stall-targeted, zero sync-structure risk:
//   1. nf quarter-slice (512 floats, 2KB) preloaded to LDS once —
//      removes 16 L2 loads (~200cy each) per thread from the epilogue
//      critical path. Epilogue nf reads: 4 distinct 16B addrs x 16-lane
//      broadcast = conflict-free. LDS 32->34KB, still 4 blocks/CU.
//   2. top-4 insert split into 4 independent chains (s2 x jt-parity),
//      merged after the loop (8 u32 inserts). Exact top-4 of the same
//      multiset (loc bits disjoint) => selected candidates bit-identical.
__global__ __launch_bounds__(256, 4) void topk_kernel(
    const unsigned short* __restrict__ xTh, const unsigned short* __restrict__ xTl,
    const float* __restrict__ nf, unsigned short* __restrict__ cand) {
  __shared__ __align__(16) unsigned short Jh[2][64 * 64];  // 2 x 8 KB
  __shared__ __align__(16) unsigned short Jl[2][64 * 64];  // 2 x 8 KB
  __shared__ __align__(16) float nfs[512];                 // 2 KB nf slice
  int bid   = blockIdx.x;
  int q     = bid & 3;               // j-quarter
  int itile = (bid >> 2) & 15;       // 16 i-tiles of 128 rows
  int b     = bid >> 6;
  int i0    = itile * 128;
  int jq0   = q * 512;
  int t = threadIdx.x;
  int w = t >> 6, lane = t & 63, quad = lane >> 4, col = lane & 15;
  int csw = col & 7;
  const unsigned short* xh = xTh + (size_t)b * N_DIM * 64;
  const unsigned short* xl = xTl + (size_t)b * N_DIM * 64;
  const float* nfb = nf + b * N_DIM;

  // I-frags (B operand) once from global: 2 i-sets x 2 k-slices.
  bf16x8 ih[2][2], il[2][2];
  #pragma unroll
  for (int s2 = 0; s2 < 2; ++s2) {
    #pragma unroll
    for (int ks = 0; ks < 2; ++ks) {
      size_t row = i0 + w * 32 + s2 * 16 + col;
      int phys = (ks * 4 + quad) ^ csw;
      ih[s2][ks] = *(const bf16x8*)(xh + row * 64 + phys * 8);
      il[s2][ks] = *(const bf16x8*)(xl + row * 64 + phys * 8);
    }
  }

  // 4 independent sorted-top-4 chains: [s2][jt&1]
  unsigned ck[2][2][4];
  #pragma unroll
  for (int s2 = 0; s2 < 2; ++s2)
    #pragma unroll
    for (int h = 0; h < 2; ++h)
      ck[s2][h][0] = ck[s2][h][1] = ck[s2][h][2] = ck[s2][h][3] = 0xFFFFFFFFu;

  int a0 = col * 64 + ((quad ^ csw) * 8);        // ks=0 frag offset (shorts)
  int a1 = col * 64 + (((4 + quad) ^ csw) * 8);  // ks=1

  const unsigned short* sbh = xh + (size_t)(jq0 + w * 16) * 64 + lane * 8;
  const unsigned short* sbl = xl + (size_t)(jq0 + w * 16) * 64 + lane * 8;
  int ldsb = w * 16 * 64;            // wave-uniform LDS base (shorts)

  // preload nf quarter slice (512 floats) — coalesced float2 per thread
  *(float2*)&nfs[t * 2] = *(const float2*)(nfb + jq0 + t * 2);

  // prologue: DMA tile 0 into buf 0
  #pragma unroll
  for (int k2 = 0; k2 < 2; ++k2) {
    GLDS16(sbh + k2 * 512, &Jh[0][ldsb + k2 * 512]);
    GLDS16(sbl + k2 * 512, &Jl[0][ldsb + k2 * 512]);
  }
  __syncthreads();                   // drain: buf0 + nfs ready

  #pragma unroll
  for (int js = 0; js < 8; ++js) {
    int cur = js & 1, nxt = cur ^ 1;

    if (js < 7) {
      #pragma unroll
      for (int k2 = 0; k2 < 2; ++k2) {
        GLDS16(sbh + (js + 1) * 4096 + k2 * 512, &Jh[nxt][ldsb + k2 * 512]);
        GLDS16(sbl + (js + 1) * 4096 + k2 * 512, &Jl[nxt][ldsb + k2 * 512]);
      }
    }

    floatx4 acc[2][4];
    #pragma unroll
    for (int s2 = 0; s2 < 2; ++s2)
      #pragma unroll
      for (int jt = 0; jt < 4; ++jt) acc[s2][jt] = (floatx4){0.f, 0.f, 0.f, 0.f};

    #pragma unroll
    for (int ks = 0; ks < 2; ++ks) {
      int ab = ks ? a1 : a0;
      #pragma unroll
      for (int jt = 0; jt < 4; ++jt) {
        bf16x8 jh = *(const bf16x8*)&Jh[cur][jt * 1024 + ab];
        bf16x8 jl = *(const bf16x8*)&Jl[cur][jt * 1024 + ab];
        #pragma unroll
        for (int s2 = 0; s2 < 2; ++s2) {
          acc[s2][jt] = __builtin_amdgcn_mfma_f32_16x16x32_bf16(jl, ih[s2][ks], acc[s2][jt], 0, 0, 0);
          acc[s2][jt] = __builtin_amdgcn_mfma_f32_16x16x32_bf16(jh, il[s2][ks], acc[s2][jt], 0, 0, 0);
          acc[s2][jt] = __builtin_amdgcn_mfma_f32_16x16x32_bf16(jh, ih[s2][ks], acc[s2][jt], 0, 0, 0);
        }
      }
    }

    // epilogue: key' = nf512[j] - 2*dot (> 0); pack (bits & ~127) |
    // (js<<4 | jt*4+r); 4 independent top-4 chains (s2 x jt-parity),
    // nf from LDS (broadcast, conflict-free).
    unsigned locb = (unsigned)(js << 4);
    #pragma unroll
    for (int jt = 0; jt < 4; ++jt) {
      float4 nv = *(const float4*)&nfs[js * 64 + quad * 4 + jt * 16];
      float nfa[4] = {nv.x, nv.y, nv.z, nv.w};
      #pragma unroll
      for (int r = 0; r < 4; ++r) {
        unsigned idbits = locb | (unsigned)(jt * 4 + r);
        #pragma unroll
        for (int s2 = 0; s2 < 2; ++s2) {
          float key = fmaf(-2.0f, acc[s2][jt][r], nfa[r]);
          unsigned u = (__float_as_uint(key) & 0xFFFFFF80u) | idbits;
          unsigned* c = ck[s2][jt & 1];
          unsigned m0 = min(c[0], u);
          unsigned m1 = med3u(c[0], u, c[1]);
          unsigned m2 = med3u(c[1], u, c[2]);
          unsigned m3 = med3u(c[2], u, c[3]);
          c[0] = m0; c[1] = m1; c[2] = m2; c[3] = m3;
        }
      }
    }
    __syncthreads();
  }

  // merge odd-parity chain into even-parity chain (exact top-4 of union)
  #pragma unroll
  for (int s2 = 0; s2 < 2; ++s2) {
    #pragma unroll
    for (int s = 0; s < 4; ++s) {
      unsigned u = ck[s2][1][s];
      unsigned* c = ck[s2][0];
      unsigned m0 = min(c[0], u);
      unsigned m1 = med3u(c[0], u, c[1]);
      unsigned m2 = med3u(c[1], u, c[2]);
      unsigned m3 = med3u(c[2], u, c[3]);
      c[0] = m0; c[1] = m1; c[2] = m2; c[3] = m3;
    }
  }

  #pragma unroll
  for (int s2 = 0; s2 < 2; ++s2) {
    int cj[4];
    unsigned cku[4];
    #pragma unroll
    for (int s = 0; s < 4; ++s) {
      unsigned loc = ck[s2][0][s] & 127u;
      cj[s] = jq0 + (int)((loc >> 4) << 6) + (int)(((loc >> 2) & 3u) << 4) +
              (quad << 2) + (int)(loc & 3u);
      cku[s] = ck[s2][0][s];
    }
    #pragma unroll
    for (int m = 16; m < 64; m <<= 1) {
      unsigned tu[4]; int tj[4];
      #pragma unroll
      for (int s = 0; s < 4; ++s) {
        tu[s] = __shfl_xor(cku[s], m, 64);
        tj[s] = __shfl_xor(cj[s], m, 64);
      }
      #pragma unroll
      for (int s = 0; s < 4; ++s) ins4p(tu[s], tj[s], cku, cj);
    }
    if (quad == 0) {
      int row = b * N_DIM + i0 + w * 32 + s2 * 16 + col;
      unsigned short* cp = cand + row * 16 + q * 4;
      cp[0] = (unsigned short)cj[0];
      cp[1] = (unsigned short)cj[1];
      cp[2] = (unsigned short)cj[2];
      cp[3] = (unsigned short)cj[3];
    }
  }
}

// ---- kernel 3: fused exact-fp64 refine + gather + conv (r6-VERBATIM;
// r9/r10 hoist experiments were neutral-to-negative and are dropped) ----
#define NT   64
#define NPAD 68
__global__ __launch_bounds__(256, 2) void conv_kernel(
    const float* __restrict__ xT, const double* __restrict__ nd,
    const unsigned short* __restrict__ cand,
    const float* __restrict__ Wt, const float* __restrict__ bias,
    float* __restrict__ out) {
  __shared__ __align__(16) float nb[C_DIM * K_NN][NPAD];  // 52224 B
  __shared__ unsigned long long tks[NT];                  // 512 B
  int bid = blockIdx.x;
  int b  = bid >> 5;
  int n0 = (bid & 31) * NT;
  const float* xtb = xT + (size_t)b * N_DIM * C_DIM;
  const double* ndb = nd + b * N_DIM;
  int t = threadIdx.x;
  int w = t >> 6, lane = t & 63;
  int cid = lane >> 2, seg = lane & 3;

  // ---- refine: 16 rows/wave, 2 rows in flight ----
  for (int g = 0; g < 8; ++g) {
    int nnA = w * 16 + 2 * g;
    int nnB = nnA + 1;
    int jA = cand[(b * N_DIM + n0 + nnA) * 16 + cid];
    int jB = cand[(b * N_DIM + n0 + nnB) * 16 + cid];
    const float* xnA = xtb + (size_t)(n0 + nnA) * C_DIM + seg * 16;
    const float* xjA = xtb + (size_t)jA * C_DIM + seg * 16;
    const float* xnB = xtb + (size_t)(n0 + nnB) * C_DIM + seg * 16;
    const float* xjB = xtb + (size_t)jB * C_DIM + seg * 16;
    float4 aA[4], bA[4], aB[4], bB[4];
    #pragma unroll
    for (int qq = 0; qq < 4; ++qq) {     // all 16 loads issued up front
      aA[qq] = *(const float4*)(xnA + qq * 4);
      bA[qq] = *(const float4*)(xjA + qq * 4);
      aB[qq] = *(const float4*)(xnB + qq * 4);
      bB[qq] = *(const float4*)(xjB + qq * 4);
    }
    double pA = 0.0, pB = 0.0;
    #pragma unroll
    for (int qq = 0; qq < 4; ++qq) {
      pA = fma((double)aA[qq].x, (double)bA[qq].x, pA);
      pA = fma((double)aA[qq].y, (double)bA[qq].y, pA);
      pA = fma((double)aA[qq].z, (double)bA[qq].z, pA);
      pA = fma((double)aA[qq].w, (double)bA[qq].w, pA);
      pB = fma((double)aB[qq].x, (double)bB[qq].x, pB);
      pB = fma((double)aB[qq].y, (double)bB[qq].y, pB);
      pB = fma((double)aB[qq].z, (double)bB[qq].z, pB);
      pB = fma((double)aB[qq].w, (double)bB[qq].w, pB);
    }
    pA += __shfl_xor(pA, 1, 64);         // reduce over seg (4 lanes)
    pA += __shfl_xor(pA, 2, 64);
    pB += __shfl_xor(pB, 1, 64);
    pB += __shfl_xor(pB, 2, 64);
    double keyA = fma(-2.0, pA, ndb[jA] + 512.0);  // > 0 always
    double keyB = fma(-2.0, pB, ndb[jB] + 512.0);
    unsigned long long uA =
        ((unsigned long long)__double_as_longlong(keyA) & ~2047ull) |
        (unsigned long long)(unsigned)jA;
    unsigned long long uB =
        ((unsigned long long)__double_as_longlong(keyB) & ~2047ull) |
        (unsigned long long)(unsigned)jB;
    // tournament top-3 across the 16 cid groups (values uniform in-group)
    unsigned long long a0 = uA, a1 = ~0ull, a2 = ~0ull;
    unsigned long long b0 = uB, b1 = ~0ull, b2 = ~0ull;
    #pragma unroll
    for (int m = 4; m < 64; m <<= 1) {
      unsigned long long q0 = __shfl_xor(a0, m, 64);
      unsigned long long q1 = __shfl_xor(a1, m, 64);
      unsigned long long q2 = __shfl_xor(a2, m, 64);
      ins3u64(q0, a0, a1, a2); ins3u64(q1, a0, a1, a2); ins3u64(q2, a0, a1, a2);
      unsigned long long r0 = __shfl_xor(b0, m, 64);
      unsigned long long r1 = __shfl_xor(b1, m, 64);
      unsigned long long r2 = __shfl_xor(b2, m, 64);
      ins3u64(r0, b0, b1, b2); ins3u64(r1, b0, b1, b2); ins3u64(r2, b0, b1, b2);
    }
    if (lane == 0) {
      tks[nnA] = (a0 & 2047ull) | ((a1 & 2047ull) << 16) | ((a2 & 2047ull) << 32);
      tks[nnB] = (b0 & 2047ull) | ((b1 & 2047ull) << 16) | ((b2 & 2047ull) << 32);
    }
  }
  __syncthreads();

  // ---- gather phase (r1 map) ----
  #pragma unroll
  for (int p = 0; p < 12; ++p) {
    int u = p * 256 + t;            // 3072 tasks: 192 rows x 16 segs
    int sg = u & 15;
    int r  = u >> 4;                // r = k*64 + n
    int k = r >> 6, n = r & 63;
    int j = (int)((tks[n] >> (16 * k)) & 2047ull);
    float4 v = *(const float4*)(xtb + (size_t)j * C_DIM + sg * 4);
    nb[(sg * 4 + 0) * 3 + k][n] = v.x;
    nb[(sg * 4 + 1) * 3 + k][n] = v.y;
    nb[(sg * 4 + 2) * 3 + k][n] = v.z;
    nb[(sg * 4 + 3) * 3 + k][n] = v.w;
  }
  __syncthreads();

  // ---- conv phase (r1 4o x 4n map: 16 distinct LDS addrs/wave) ----
  int ng = t & 15, og = t >> 4;
  float acc[4][4];
  #pragma unroll
  for (int oo = 0; oo < 4; ++oo) {
    float bv = bias[(og << 2) + oo];
    #pragma unroll
    for (int nn2 = 0; nn2 < 4; ++nn2) acc[oo][nn2] = bv;
  }
  const float* nbp = &nb[0][0] + (ng << 2);
  const float* wtp = Wt + (og << 2);
  #pragma unroll 4
  for (int ckk = 0; ckk < C_DIM * K_NN; ++ckk) {
    float4 nv = *(const float4*)(nbp + ckk * NPAD);
    float4 wv = *(const float4*)(wtp + ckk * O_DIM);
    float na[4] = {nv.x, nv.y, nv.z, nv.w};
    float wa[4] = {wv.x, wv.y, wv.z, wv.w};
    #pragma unroll
    for (int oo = 0; oo < 4; ++oo)
      #pragma unroll
      for (int nn2 = 0; nn2 < 4; ++nn2)
        acc[oo][nn2] = fmaf(wa[oo], na[nn2], acc[oo][nn2]);
  }
  #pragma unroll
  for (int oo = 0; oo < 4; ++oo) {
    int o = (og << 2) + oo;
    float4 v; v.x = acc[oo][0]; v.y = acc[oo][1]; v.z = acc[oo][2]; v.w = acc[oo][3];
    *(float4*)&out[(size_t)(b * O_DIM + o) * N_DIM + n0 + (ng << 2)] = v;
  }
}

extern "C" void kernel_launch(void* const* d_in, const int* in_sizes, int n_in,
                              void* d_out, int out_size, void* d_ws, size_t ws_size,
                              hipStream_t stream) {
  const float* x    = (const float*)d_in[0];   // [B][C][N]
  const float* W    = (const float*)d_in[1];   // [O][C][K]
  const float* bias = (const float*)d_in[2];   // [O]
  float* out = (float*)d_out;                  // [B][O][N]
  char* ws = (char*)d_ws;
  // ws layout (bytes):
  //   xT   fp32 [B][N][C]           @ 0         (8 MB)
  //   xTh  bf16 [B][N][C] swizzled  @ 8388608   (4 MB)
  //   xTl  bf16 [B][N][C] swizzled  @ 12582912  (4 MB)
  //   nd   fp64 [B*N]               @ 16777216  (256 KB)
  //   nf   fp32 [B*N] (norm+512)    @ 17039360  (128 KB)
  //   cand u16  [B*N][16]           @ 17170432  (1 MB)
  //   Wt   fp32 [C*K][O]            @ 18219008  (48 KB)
  float*          xT  = (float*)ws;
  unsigned short* xTh = (unsigned short*)(ws + 8388608);
  unsigned short* xTl = (unsigned short*)(ws + 12582912);
  double*         nd  = (double*)(ws + 16777216);
  float*          nfp = (float*)(ws + 17039360);
  unsigned short* cd  = (unsigned short*)(ws + 17170432);
  float*          Wt  = (float*)(ws + 18219008);

  prep_kernel<<<512 + 48, 256, 0, stream>>>(x, xT, xTh, xTl, nd, nfp, W, Wt);
  topk_kernel<<<B_DIM * 16 * 4, 256, 0, stream>>>(xTh, xTl, nfp, cd);
  conv_kernel<<<B_DIM * (N_DIM / NT), 256, 0, stream>>>(xT, nd, cd, Wt, bias, out);
}

// Round 12
// 139.128 us; speedup vs baseline: 1.0121x; 1.0121x over previous
//
#include <hip/hip_runtime.h>
#include <cfloat>
#include <climits>

#define B_DIM 16
#define C_DIM 64
#define N_DIM 2048
#define O_DIM 64
#define K_NN  3

typedef __attribute__((ext_vector_type(8))) short bf16x8;
typedef __attribute__((ext_vector_type(4))) float floatx4;

// async global->LDS DMA, 16B/lane: LDS dest = uniform base + lane*16
#define GLDS16(gsrc, ldst)                                        \
  __builtin_amdgcn_global_load_lds(                               \
      (const __attribute__((address_space(1))) void*)(gsrc),      \
      (__attribute__((address_space(3))) void*)(ldst), 16, 0, 0)

__device__ __forceinline__ unsigned short f32_to_bf16_rne(float f) {
  unsigned int u = __float_as_uint(f);
  return (unsigned short)((u + 0x7fffu + ((u >> 16) & 1u)) >> 16);
}
__device__ __forceinline__ float bf16_to_f32(unsigned short h) {
  return __uint_as_float(((unsigned int)h) << 16);
}

// med3 on u32 (compiler pattern-matches to v_med3_u32)
__device__ __forceinline__ unsigned med3u(unsigned a, unsigned b, unsigned c) {
  unsigned mn = min(a, b), mx = max(a, b);
  return max(mn, min(mx, c));
}

// paired (packed-key, j) branchless top-4 insert — merge phase only
__device__ __forceinline__ void ins4p(unsigned u, int jv, unsigned* k, int* j) {
  bool c3 = u < k[3], c2 = u < k[2], c1 = u < k[1], c0 = u < k[0];
  k[3] = c2 ? k[2] : (c3 ? u  : k[3]);
  j[3] = c2 ? j[2] : (c3 ? jv : j[3]);
  k[2] = c1 ? k[1] : (c2 ? u  : k[2]);
  j[2] = c1 ? j[1] : (c2 ? jv : j[2]);
  k[1] = c0 ? k[0] : (c1 ? u  : k[1]);
  j[1] = c0 ? j[0] : (c1 ? jv : j[1]);
  k[0] = c0 ? u  : k[0];
  j[0] = c0 ? jv : j[0];
}

// branchless sorted-top-3 insert on u64 keys
__device__ __forceinline__ void ins3u64(unsigned long long v,
                                        unsigned long long& k0,
                                        unsigned long long& k1,
                                        unsigned long long& k2) {
  bool c0 = v < k0, c1 = v < k1, c2 = v < k2;
  k2 = c1 ? k1 : (c2 ? v : k2);
  k1 = c0 ? k0 : (c1 ? v : k1);
  k0 = c0 ? v : k0;
}

// ---- kernel 1: x -> xT fp32 [B][N][C], bf16 hi/lo split (chunk-swizzled:
// 16B chunk q of row n stored at q^(n&7)), fp64 norms nd, fp32 norms+512.
// Blocks >= 512 do the W transpose. ----
__global__ __launch_bounds__(256) void prep_kernel(
    const float* __restrict__ x, float* __restrict__ xT,
    unsigned short* __restrict__ xTh, unsigned short* __restrict__ xTl,
    double* __restrict__ nd, float* __restrict__ nf,
    const float* __restrict__ W, float* __restrict__ Wt) {
  int bid = blockIdx.x;
  int t = threadIdx.x;
  if (bid >= 512) {                  // W transpose: 48 blocks
    int t2 = (bid - 512) * 256 + t;  // 12288 = O * C * K
    int o  = t2 / (C_DIM * K_NN);
    int ck = t2 - o * (C_DIM * K_NN);
    Wt[ck * O_DIM + o] = W[t2];
    return;
  }
  __shared__ __align__(16) float xs[C_DIM][68];
  int b  = bid >> 5;
  int n0 = (bid & 31) * 64;
  const float* xb = x + (size_t)b * C_DIM * N_DIM;
  #pragma unroll
  for (int r = 0; r < 4; ++r) {
    int idx = r * 256 + t;           // 1024 float4 tasks
    int c = idx >> 4;
    int qq = idx & 15;
    *(float4*)&xs[c][qq * 4] = *(const float4*)(xb + (size_t)c * N_DIM + n0 + qq * 4);
  }
  __syncthreads();
  int n = t >> 2, cg = t & 3;        // 64 n x 4 c-groups of 16
  float v[16];
  #pragma unroll
  for (int cc = 0; cc < 16; ++cc) v[cc] = xs[cg * 16 + cc][n];
  double ps = 0.0;
  #pragma unroll
  for (int cc = 0; cc < 16; ++cc) ps = fma((double)v[cc], (double)v[cc], ps);
  ps += __shfl_xor(ps, 1, 64);
  ps += __shfl_xor(ps, 2, 64);       // lanes t^1,t^2 share n
  size_t row = (size_t)b * N_DIM + n0 + n;
  #pragma unroll
  for (int qq = 0; qq < 4; ++qq) {
    float4 wv; wv.x = v[qq*4]; wv.y = v[qq*4+1]; wv.z = v[qq*4+2]; wv.w = v[qq*4+3];
    *(float4*)&xT[row * C_DIM + cg * 16 + qq * 4] = wv;
  }
  unsigned short hh[16], ll[16];
  #pragma unroll
  for (int cc = 0; cc < 16; ++cc) {
    hh[cc] = f32_to_bf16_rne(v[cc]);
    ll[cc] = f32_to_bf16_rne(v[cc] - bf16_to_f32(hh[cc]));
  }
  #pragma unroll
  for (int e = 0; e < 2; ++e) {
    int phys = (2 * cg + e) ^ (n & 7);
    unsigned int hp[4], lp[4];
    #pragma unroll
    for (int xk = 0; xk < 4; ++xk) {
      hp[xk] = (unsigned)hh[e*8 + 2*xk] | ((unsigned)hh[e*8 + 2*xk + 1] << 16);
      lp[xk] = (unsigned)ll[e*8 + 2*xk] | ((unsigned)ll[e*8 + 2*xk + 1] << 16);
    }
    ((uint4*)xTh)[row * 8 + phys] = *(uint4*)hp;
    ((uint4*)xTl)[row * 8 + phys] = *(uint4*)lp;
  }
  if (cg == 0) {
    nd[row] = ps;
    nf[row] = (float)ps + 512.0f;    // pre-biased: key' = fma(-2,acc,nf) > 0
  }
}

// ---- kernel 2: split-bf16 MFMA distance sweep, packed-u32 top-4,
// double-buffered global_load_lds staging ----
// ROUND-12: r6 sync structure UNCHANGED (2-buffer, one __syncthreads per
// j-step; r7's counted-vmcnt rework regressed 2.2x; r11's epilogue
// changes were neutral => the stall is the per-step drain cadence).
// Change: i-rows/block 128 -> 256 (8 i-tiles). Mechanism:
//   - each J-frag LDS read feeds 12 MFMAs (was 6)
//   - total DMA + LDS-read traffic per CU HALVES (512 blocks stage the
//     same 128KB each instead of 1024 blocks)
//   - barrier-drain events per CU halve; compute per drain doubles
// grid = 16*8*4 = 512 blocks = 2 blocks/CU (LDS 32KB). VGPR ~170 =>
// __launch_bounds__(256,2) (cap 256, no spill). Epilogue/keys/decode
// r6-verbatim => selection bit-identical.
__global__ __launch_bounds__(256, 2) void topk_kernel(
    const unsigned short* __restrict__ xTh, const unsigned short* __restrict__ xTl,
    const float* __restrict__ nf, unsigned short* __restrict__ cand) {
  __shared__ __align__(16) unsigned short Jh[2][64 * 64];  // 2 x 8 KB
  __shared__ __align__(16) unsigned short Jl[2][64 * 64];  // 2 x 8 KB
  int bid   = blockIdx.x;
  int q     = bid & 3;               // j-quarter
  int itile = (bid >> 2) & 7;        // 8 i-tiles of 256 rows
  int b     = bid >> 5;
  int i0    = itile * 256;
  int jq0   = q * 512;
  int t = threadIdx.x;
  int w = t >> 6, lane = t & 63, quad = lane >> 4, col = lane & 15;
  int csw = col & 7;
  const unsigned short* xh = xTh + (size_t)b * N_DIM * 64;
  const unsigned short* xl = xTl + (size_t)b * N_DIM * 64;
  const float* nfb = nf + b * N_DIM;

  // I-frags (B operand) once from global: 4 i-sets x 2 k-slices.
  // wave w owns rows [i0 + w*64, i0 + w*64 + 64). row&7 == col&7 == csw.
  bf16x8 ih[4][2], il[4][2];
  #pragma unroll
  for (int s2 = 0; s2 < 4; ++s2) {
    #pragma unroll
    for (int ks = 0; ks < 2; ++ks) {
      size_t row = i0 + w * 64 + s2 * 16 + col;
      int phys = (ks * 4 + quad) ^ csw;
      ih[s2][ks] = *(const bf16x8*)(xh + row * 64 + phys * 8);
      il[s2][ks] = *(const bf16x8*)(xl + row * 64 + phys * 8);
    }
  }

  unsigned ck[4][4];
  #pragma unroll
  for (int s2 = 0; s2 < 4; ++s2)
    ck[s2][0] = ck[s2][1] = ck[s2][2] = ck[s2][3] = 0xFFFFFFFFu;

  int a0 = col * 64 + ((quad ^ csw) * 8);        // ks=0 frag offset (shorts)
  int a1 = col * 64 + (((4 + quad) ^ csw) * 8);  // ks=1

  const unsigned short* sbh = xh + (size_t)(jq0 + w * 16) * 64 + lane * 8;
  const unsigned short* sbl = xl + (size_t)(jq0 + w * 16) * 64 + lane * 8;
  int ldsb = w * 16 * 64;            // wave-uniform LDS base (shorts)

  // prologue: DMA tile 0 into buf 0
  #pragma unroll
  for (int k2 = 0; k2 < 2; ++k2) {
    GLDS16(sbh + k2 * 512, &Jh[0][ldsb + k2 * 512]);
    GLDS16(sbl + k2 * 512, &Jl[0][ldsb + k2 * 512]);
  }
  __syncthreads();                   // drain: buf0 ready

  #pragma unroll
  for (int js = 0; js < 8; ++js) {
    int cur = js & 1, nxt = cur ^ 1;
    int j0 = jq0 + js * 64;

    if (js < 7) {
      #pragma unroll
      for (int k2 = 0; k2 < 2; ++k2) {
        GLDS16(sbh + (js + 1) * 4096 + k2 * 512, &Jh[nxt][ldsb + k2 * 512]);
        GLDS16(sbl + (js + 1) * 4096 + k2 * 512, &Jl[nxt][ldsb + k2 * 512]);
      }
    }

    floatx4 acc[4][4];
    #pragma unroll
    for (int s2 = 0; s2 < 4; ++s2)
      #pragma unroll
      for (int jt = 0; jt < 4; ++jt) acc[s2][jt] = (floatx4){0.f, 0.f, 0.f, 0.f};

    #pragma unroll
    for (int ks = 0; ks < 2; ++ks) {
      int ab = ks ? a1 : a0;
      #pragma unroll
      for (int jt = 0; jt < 4; ++jt) {
        bf16x8 jh = *(const bf16x8*)&Jh[cur][jt * 1024 + ab];
        bf16x8 jl = *(const bf16x8*)&Jl[cur][jt * 1024 + ab];
        #pragma unroll
        for (int s2 = 0; s2 < 4; ++s2) {
          acc[s2][jt] = __builtin_amdgcn_mfma_f32_16x16x32_bf16(jl, ih[s2][ks], acc[s2][jt], 0, 0, 0);
          acc[s2][jt] = __builtin_amdgcn_mfma_f32_16x16x32_bf16(jh, il[s2][ks], acc[s2][jt], 0, 0, 0);
          acc[s2][jt] = __builtin_amdgcn_mfma_f32_16x16x32_bf16(jh, ih[s2][ks], acc[s2][jt], 0, 0, 0);
        }
      }
    }

    // epilogue: key' = nf512[j] - 2*dot (> 0); pack (bits & ~127) |
    // (js<<4 | jt*4+r); sorted top-4 via min + 3 med3, four independent
    // chains (one per i-set) sharing each nf load. (r6 form, 4 i-sets.)
    unsigned locb = (unsigned)(js << 4);
    int jb = j0 + quad * 4;
    #pragma unroll
    for (int jt = 0; jt < 4; ++jt) {
      float4 nv = *(const float4*)(nfb + jb + jt * 16);
      float nfa[4] = {nv.x, nv.y, nv.z, nv.w};
      #pragma unroll
      for (int r = 0; r < 4; ++r) {
        unsigned idbits = locb | (unsigned)(jt * 4 + r);
        #pragma unroll
        for (int s2 = 0; s2 < 4; ++s2) {
          float key = fmaf(-2.0f, acc[s2][jt][r], nfa[r]);
          unsigned u = (__float_as_uint(key) & 0xFFFFFF80u) | idbits;
          unsigned m0 = min(ck[s2][0], u);
          unsigned m1 = med3u(ck[s2][0], u, ck[s2][1]);
          unsigned m2 = med3u(ck[s2][1], u, ck[s2][2]);
          unsigned m3 = med3u(ck[s2][2], u, ck[s2][3]);
          ck[s2][0] = m0; ck[s2][1] = m1; ck[s2][2] = m2; ck[s2][3] = m3;
        }
      }
    }
    __syncthreads();
  }

  // decode stream-local ids -> global j, then paired merge across the
  // 4 quads holding the same i-row.
  #pragma unroll
  for (int s2 = 0; s2 < 4; ++s2) {
    int cj[4];
    unsigned cku[4];
    #pragma unroll
    for (int s = 0; s < 4; ++s) {
      unsigned loc = ck[s2][s] & 127u;
      cj[s] = jq0 + (int)((loc >> 4) << 6) + (int)(((loc >> 2) & 3u) << 4) +
              (quad << 2) + (int)(loc & 3u);
      cku[s] = ck[s2][s];
    }
    #pragma unroll
    for (int m = 16; m < 64; m <<= 1) {
      unsigned tu[4]; int tj[4];
      #pragma unroll
      for (int s = 0; s < 4; ++s) {
        tu[s] = __shfl_xor(cku[s], m, 64);
        tj[s] = __shfl_xor(cj[s], m, 64);
      }
      #pragma unroll
      for (int s = 0; s < 4; ++s) ins4p(tu[s], tj[s], cku, cj);
    }
    if (quad == 0) {
      int row = b * N_DIM + i0 + w * 64 + s2 * 16 + col;
      unsigned short* cp = cand + row * 16 + q * 4;
      cp[0] = (unsigned short)cj[0];
      cp[1] = (unsigned short)cj[1];
      cp[2] = (unsigned short)cj[2];
      cp[3] = (unsigned short)cj[3];
    }
  }
}

// ---- kernel 3: fused exact-fp64 refine + gather + conv (r6-VERBATIM) ----
#define NT   64
#define NPAD 68
__global__ __launch_bounds__(256, 2) void conv_kernel(
    const float* __restrict__ xT, const double* __restrict__ nd,
    const unsigned short* __restrict__ cand,
    const float* __restrict__ Wt, const float* __restrict__ bias,
    float* __restrict__ out) {
  __shared__ __align__(16) float nb[C_DIM * K_NN][NPAD];  // 52224 B
  __shared__ unsigned long long tks[NT];                  // 512 B
  int bid = blockIdx.x;
  int b  = bid >> 5;
  int n0 = (bid & 31) * NT;
  const float* xtb = xT + (size_t)b * N_DIM * C_DIM;
  const double* ndb = nd + b * N_DIM;
  int t = threadIdx.x;
  int w = t >> 6, lane = t & 63;
  int cid = lane >> 2, seg = lane & 3;

  // ---- refine: 16 rows/wave, 2 rows in flight ----
  for (int g = 0; g < 8; ++g) {
    int nnA = w * 16 + 2 * g;
    int nnB = nnA + 1;
    int jA = cand[(b * N_DIM + n0 + nnA) * 16 + cid];
    int jB = cand[(b * N_DIM + n0 + nnB) * 16 + cid];
    const float* xnA = xtb + (size_t)(n0 + nnA) * C_DIM + seg * 16;
    const float* xjA = xtb + (size_t)jA * C_DIM + seg * 16;
    const float* xnB = xtb + (size_t)(n0 + nnB) * C_DIM + seg * 16;
    const float* xjB = xtb + (size_t)jB * C_DIM + seg * 16;
    float4 aA[4], bA[4], aB[4], bB[4];
    #pragma unroll
    for (int qq = 0; qq < 4; ++qq) {     // all 16 loads issued up front
      aA[qq] = *(const float4*)(xnA + qq * 4);
      bA[qq] = *(const float4*)(xjA + qq * 4);
      aB[qq] = *(const float4*)(xnB + qq * 4);
      bB[qq] = *(const float4*)(xjB + qq * 4);
    }
    double pA = 0.0, pB = 0.0;
    #pragma unroll
    for (int qq = 0; qq < 4; ++qq) {
      pA = fma((double)aA[qq].x, (double)bA[qq].x, pA);
      pA = fma((double)aA[qq].y, (double)bA[qq].y, pA);
      pA = fma((double)aA[qq].z, (double)bA[qq].z, pA);
      pA = fma((double)aA[qq].w, (double)bA[qq].w, pA);
      pB = fma((double)aB[qq].x, (double)bB[qq].x, pB);
      pB = fma((double)aB[qq].y, (double)bB[qq].y, pB);
      pB = fma((double)aB[qq].z, (double)bB[qq].z, pB);
      pB = fma((double)aB[qq].w, (double)bB[qq].w, pB);
    }
    pA += __shfl_xor(pA, 1, 64);         // reduce over seg (4 lanes)
    pA += __shfl_xor(pA, 2, 64);
    pB += __shfl_xor(pB, 1, 64);
    pB += __shfl_xor(pB, 2, 64);
    double keyA = fma(-2.0, pA, ndb[jA] + 512.0);  // > 0 always
    double keyB = fma(-2.0, pB, ndb[jB] + 512.0);
    unsigned long long uA =
        ((unsigned long long)__double_as_longlong(keyA) & ~2047ull) |
        (unsigned long long)(unsigned)jA;
    unsigned long long uB =
        ((unsigned long long)__double_as_longlong(keyB) & ~2047ull) |
        (unsigned long long)(unsigned)jB;
    // tournament top-3 across the 16 cid groups (values uniform in-group)
    unsigned long long a0 = uA, a1 = ~0ull, a2 = ~0ull;
    unsigned long long b0 = uB, b1 = ~0ull, b2 = ~0ull;
    #pragma unroll
    for (int m = 4; m < 64; m <<= 1) {
      unsigned long long q0 = __shfl_xor(a0, m, 64);
      unsigned long long q1 = __shfl_xor(a1, m, 64);
      unsigned long long q2 = __shfl_xor(a2, m, 64);
      ins3u64(q0, a0, a1, a2); ins3u64(q1, a0, a1, a2); ins3u64(q2, a0, a1, a2);
      unsigned long long r0 = __shfl_xor(b0, m, 64);
      unsigned long long r1 = __shfl_xor(b1, m, 64);
      unsigned long long r2 = __shfl_xor(b2, m, 64);
      ins3u64(r0, b0, b1, b2); ins3u64(r1, b0, b1, b2); ins3u64(r2, b0, b1, b2);
    }
    if (lane == 0) {
      tks[nnA] = (a0 & 2047ull) | ((a1 & 2047ull) << 16) | ((a2 & 2047ull) << 32);
      tks[nnB] = (b0 & 2047ull) | ((b1 & 2047ull) << 16) | ((b2 & 2047ull) << 32);
    }
  }
  __syncthreads();

  // ---- gather phase (r1 map) ----
  #pragma unroll
  for (int p = 0; p < 12; ++p) {
    int u = p * 256 + t;            // 3072 tasks: 192 rows x 16 segs
    int sg = u & 15;
    int r  = u >> 4;                // r = k*64 + n
    int k = r >> 6, n = r & 63;
    int j = (int)((tks[n] >> (16 * k)) & 2047ull);
    float4 v = *(const float4*)(xtb + (size_t)j * C_DIM + sg * 4);
    nb[(sg * 4 + 0) * 3 + k][n] = v.x;
    nb[(sg * 4 + 1) * 3 + k][n] = v.y;
    nb[(sg * 4 + 2) * 3 + k][n] = v.z;
    nb[(sg * 4 + 3) * 3 + k][n] = v.w;
  }
  __syncthreads();

  // ---- conv phase (r1 4o x 4n map: 16 distinct LDS addrs/wave) ----
  int ng = t & 15, og = t >> 4;
  float acc[4][4];
  #pragma unroll
  for (int oo = 0; oo < 4; ++oo) {
    float bv = bias[(og << 2) + oo];
    #pragma unroll
    for (int nn2 = 0; nn2 < 4; ++nn2) acc[oo][nn2] = bv;
  }
  const float* nbp = &nb[0][0] + (ng << 2);
  const float* wtp = Wt + (og << 2);
  #pragma unroll 4
  for (int ckk = 0; ckk < C_DIM * K_NN; ++ckk) {
    float4 nv = *(const float4*)(nbp + ckk * NPAD);
    float4 wv = *(const float4*)(wtp + ckk * O_DIM);
    float na[4] = {nv.x, nv.y, nv.z, nv.w};
    float wa[4] = {wv.x, wv.y, wv.z, wv.w};
    #pragma unroll
    for (int oo = 0; oo < 4; ++oo)
      #pragma unroll
      for (int nn2 = 0; nn2 < 4; ++nn2)
        acc[oo][nn2] = fmaf(wa[oo], na[nn2], acc[oo][nn2]);
  }
  #pragma unroll
  for (int oo = 0; oo < 4; ++oo) {
    int o = (og << 2) + oo;
    float4 v; v.x = acc[oo][0]; v.y = acc[oo][1]; v.z = acc[oo][2]; v.w = acc[oo][3];
    *(float4*)&out[(size_t)(b * O_DIM + o) * N_DIM + n0 + (ng << 2)] = v;
  }
}

extern "C" void kernel_launch(void* const* d_in, const int* in_sizes, int n_in,
                              void* d_out, int out_size, void* d_ws, size_t ws_size,
                              hipStream_t stream) {
  const float* x    = (const float*)d_in[0];   // [B][C][N]
  const float* W    = (const float*)d_in[1];   // [O][C][K]
  const float* bias = (const float*)d_in[2];   // [O]
  float* out = (float*)d_out;                  // [B][O][N]
  char* ws = (char*)d_ws;
  // ws layout (bytes):
  //   xT   fp32 [B][N][C]           @ 0         (8 MB)
  //   xTh  bf16 [B][N][C] swizzled  @ 8388608   (4 MB)
  //   xTl  bf16 [B][N][C] swizzled  @ 12582912  (4 MB)
  //   nd   fp64 [B*N]               @ 16777216  (256 KB)
  //   nf   fp32 [B*N] (norm+512)    @ 17039360  (128 KB)
  //   cand u16  [B*N][16]           @ 17170432  (1 MB)
  //   Wt   fp32 [C*K][O]            @ 18219008  (48 KB)
  float*          xT  = (float*)ws;
  unsigned short* xTh = (unsigned short*)(ws + 8388608);
  unsigned short* xTl = (unsigned short*)(ws + 12582912);
  double*         nd  = (double*)(ws + 16777216);
  float*          nfp = (float*)(ws + 17039360);
  unsigned short* cd  = (unsigned short*)(ws + 17170432);
  float*          Wt  = (float*)(ws + 18219008);

  prep_kernel<<<512 + 48, 256, 0, stream>>>(x, xT, xTh, xTl, nd, nfp, W, Wt);
  topk_kernel<<<B_DIM * 8 * 4, 256, 0, stream>>>(xTh, xTl, nfp, cd);
  conv_kernel<<<B_DIM * (N_DIM / NT), 256, 0, stream>>>(xT, nd, cd, Wt, bias, out);
}